// Round 17
// baseline (271.373 us; speedup 1.0000x reference)
//
#include <hip/hip_runtime.h>
#include <hip/hip_bf16.h>
#include <stdint.h>

// Problem: b=32, s=256, h=1024, 5 options.
// out = 0.5 * sum_n V_n @ o_n,  V_n = sum_{i!=n} softmax_k(q_i . o_k)_n,  q_i = o_i @ W
// bias is softmax-shift-invariant -> ignored.
// Round 17: cast_all eliminated. qgemm = r14 schedule (BK=64, one
// vmcnt(0)+barrier per tile) with A reg-staged from fp32 (cast in-reg,
// swizzled ds_write) and Obf written as a side product by ct==0 blocks.
// B (Wt) stays gload_lds in-phase. gram64 v2 / pvgemm / cast_trW frozen.

#define BB 32
#define SS 256
#define HH 1024

typedef __attribute__((ext_vector_type(4))) float f32x4;
typedef __attribute__((ext_vector_type(8))) __bf16 bf16x8;
typedef __attribute__((ext_vector_type(4))) __bf16 bf16x4;

__device__ constexpr int PAIR(int i, int n) { return i * 4 + (n > i ? n - 1 : n); }

__device__ __forceinline__ void gload_lds16(const void* g, void* l) {
  __builtin_amdgcn_global_load_lds((const __attribute__((address_space(1))) void*)g,
                                   (__attribute__((address_space(3))) void*)l, 16, 0, 0);
}

__global__ void canary(float* out, float v) { out[0] = v; }

// ---------------------------------------------------------------------------
// W (1024x1024 fp32) -> Wt (bf16, transposed). 64x64 tiles, grid 256.
__global__ __launch_bounds__(256) void cast_trW(const float* __restrict__ src,
                                                __bf16* __restrict__ dstT)
{
  __shared__ __bf16 tile[64][72];
  int ct = blockIdx.x & 15, rt = blockIdx.x >> 4;
  const float* s = src + (long)(rt * 64) * 1024 + ct * 64;
  int t = threadIdx.x;
#pragma unroll
  for (int p = 0; p < 4; p++) {
    int c = t + p * 256;
    int row = c >> 4, c4 = c & 15;
    float4 v = *(const float4*)(s + (long)row * 1024 + c4 * 4);
    bf16x4 h;
    h[0] = (__bf16)v.x; h[1] = (__bf16)v.y; h[2] = (__bf16)v.z; h[3] = (__bf16)v.w;
    *(bf16x4*)&tile[row][c4 * 4] = h;
  }
  __syncthreads();
#pragma unroll
  for (int p = 0; p < 4; p++) {
    int c = t + p * 256;
    int hr = c >> 4, s4 = c & 15;
    bf16x4 h;
    h[0] = tile[s4 * 4 + 0][hr];
    h[1] = tile[s4 * 4 + 1][hr];
    h[2] = tile[s4 * 4 + 2][hr];
    h[3] = tile[s4 * 4 + 3][hr];
    *(bf16x4*)(dstT + (long)(ct * 64 + hr) * 1024 + rt * 64 + s4 * 4) = h;
  }
}

// ---------------------------------------------------------------------------
// qgemm_f32: Q = cast(A32) @ Wt, and writes Obf (bf16 copy of A) from ct==0
// blocks. 256x256 tile, 512 thr, 8 waves (2x4), BK=64, 2x64KB dbuf.
// r14 schedule: 4 phases/tile (B gload staged in-phase), one vmcnt(0)+barrier
// per tile; A fp32->reg->cast->swizzled ds_write between tiles.
__global__ __launch_bounds__(512, 2) void qgemm_f32(
    const float* p0, const float* p1, const float* p2, const float* p3, const float* p4,
    const __bf16* __restrict__ Bt, __bf16* __restrict__ Qb, __bf16* __restrict__ Obf)
{
  __shared__ __align__(16) char ldsb[2 * 65536];  // per buf: A[32K] B[32K]
  int lin = blockIdx.x;
  int xcd = lin & 7, idx = lin >> 3;         // 640 = 8 x 80 (bijective)
  int rt = xcd * 20 + (idx >> 2), ct = idx & 3;
  int m = rt >> 5;                           // option index (block-uniform)
  const float* A32 = m == 0 ? p0 : m == 1 ? p1 : m == 2 ? p2 : m == 3 ? p3 : p4;
  long arow0 = (long)(rt & 31) * 256;        // row base within option
  int t = threadIdx.x, l = t & 63, w = t >> 6;
  int wr = w >> 2, wc = w & 3;               // wave patch: 128 x 64
  f32x4 acc[8][4] = {};

  // A staging: 4 chunks c = t + 512p; row=c>>3, slot=c&7 (16B bf16 = 32B fp32).
  // ds_write addr swizzled: slot ^ (row&7). Obf store at natural position.
  const float* ga[4];
  __bf16* gob[4];
  int wda[4];
#pragma unroll
  for (int p = 0; p < 4; p++) {
    int c = t + 512 * p;
    int row = c >> 3, slot = c & 7;
    ga[p] = A32 + (arow0 + row) * 1024 + slot * 8;
    gob[p] = Obf + (long)(rt * 256 + row) * 1024 + slot * 8;
    wda[p] = row * 128 + ((slot ^ (row & 7)) << 4);
  }
  // B staging (gload_lds): source slot pre-swizzled, linear LDS dest.
  const char* gb[4];
  int wdb[4];
#pragma unroll
  for (int p = 0; p < 4; p++) {
    int c = t + 512 * p;
    int row = c >> 3;
    int sg = (c & 7) ^ (row & 7);
    gb[p] = (const char*)(Bt + (long)(ct * 256 + row) * 1024 + sg * 8);
    wdb[p] = 32768 + w * 1024 + p * 8192;    // wave-uniform; HW adds lane*16
  }
  f32x4 fa0[4], fa1[4];                      // A fp32 regs (next tile)

#define LOADS_A                                                   \
  {                                                               \
    _Pragma("unroll") for (int p = 0; p < 4; p++) {               \
      fa0[p] = *(const f32x4*)ga[p];                              \
      fa1[p] = *(const f32x4*)(ga[p] + 4);                        \
      ga[p] += 64;                                                \
    }                                                             \
  }
#define CVTWR(BUF)                                                \
  {                                                               \
    char* base = ldsb + (BUF) * 65536;                            \
    _Pragma("unroll") for (int p = 0; p < 4; p++) {               \
      bf16x8 h;                                                   \
      h[0] = (__bf16)fa0[p][0]; h[1] = (__bf16)fa0[p][1];         \
      h[2] = (__bf16)fa0[p][2]; h[3] = (__bf16)fa0[p][3];         \
      h[4] = (__bf16)fa1[p][0]; h[5] = (__bf16)fa1[p][1];         \
      h[6] = (__bf16)fa1[p][2]; h[7] = (__bf16)fa1[p][3];         \
      *(bf16x8*)(base + wda[p]) = h;                              \
      if (ct == 0) *(bf16x8*)gob[p] = h;                          \
      gob[p] += 64;                                               \
    }                                                             \
  }

  int lr = l & 15, sl = l >> 4;
  int sx0 = (sl ^ (lr & 7)) * 16;        // k-half 0
  int sx1 = ((4 | sl) ^ (lr & 7)) * 16;  // k-half 1
  int arow = (wr * 128 + lr) * 128;            // + i*2048
  int brow = 32768 + (wc * 64 + lr) * 128;     // + j*2048

#define TILE(CUR, DOSTAGE)                                                             \
  {                                                                                    \
    const char* base = ldsb + (CUR) * 65536;                                           \
    char* sbase = ldsb + ((CUR) ^ 1) * 65536;                                          \
    bf16x8 bfr[4][2], af[2][2];                                                        \
    _Pragma("unroll") for (int j = 0; j < 4; j++) {                                    \
      bfr[j][0] = *(const bf16x8*)(base + brow + j * 2048 + sx0);                      \
      bfr[j][1] = *(const bf16x8*)(base + brow + j * 2048 + sx1);                      \
    }                                                                                  \
    _Pragma("unroll") for (int ph = 0; ph < 4; ph++) {                                 \
      if (DOSTAGE) {                                                                   \
        gload_lds16(gb[ph], sbase + wdb[ph]);                                          \
        gb[ph] += 128;                                                                 \
      }                                                                                \
      _Pragma("unroll") for (int ii = 0; ii < 2; ii++) {                               \
        int i = ph * 2 + ii;                                                           \
        af[ii][0] = *(const bf16x8*)(base + arow + i * 2048 + sx0);                    \
        af[ii][1] = *(const bf16x8*)(base + arow + i * 2048 + sx1);                    \
      }                                                                                \
      __builtin_amdgcn_s_setprio(1);                                                   \
      _Pragma("unroll") for (int ii = 0; ii < 2; ii++)                                 \
        _Pragma("unroll") for (int j = 0; j < 4; j++) {                                \
          acc[ph * 2 + ii][j] = __builtin_amdgcn_mfma_f32_16x16x32_bf16(               \
              af[ii][0], bfr[j][0], acc[ph * 2 + ii][j], 0, 0, 0);                     \
          acc[ph * 2 + ii][j] = __builtin_amdgcn_mfma_f32_16x16x32_bf16(               \
              af[ii][1], bfr[j][1], acc[ph * 2 + ii][j], 0, 0, 0);                     \
        }                                                                              \
      __builtin_amdgcn_s_setprio(0);                                                   \
    }                                                                                  \
  }

#define BODY(CUR, T)                                              \
  {                                                               \
    TILE(CUR, (T) < 15)                                           \
    if ((T) < 15) {                                               \
      asm volatile("s_waitcnt vmcnt(0)" ::: "memory");            \
      CVTWR((CUR) ^ 1)                                            \
      if ((T) < 14) { LOADS_A }                                   \
    }                                                             \
    asm volatile("s_waitcnt lgkmcnt(0)" ::: "memory");            \
    __builtin_amdgcn_s_barrier();                                 \
  }

  // prologue: tile0 A regs + B gloads -> buf0; write tile0; load tile1 A regs
  LOADS_A
#pragma unroll
  for (int p = 0; p < 4; p++) {
    gload_lds16(gb[p], ldsb + wdb[p]);
    gb[p] += 128;
  }
  asm volatile("s_waitcnt vmcnt(0)" ::: "memory");
  CVTWR(0)
  LOADS_A
  asm volatile("s_waitcnt lgkmcnt(0)" ::: "memory");
  __builtin_amdgcn_s_barrier();

  for (int tt = 0; tt < 15; tt++) {
    BODY(tt & 1, tt)
  }
  TILE(1, 0)  // tile 15
#undef BODY
#undef TILE
#undef CVTWR
#undef LOADS_A

#pragma unroll
  for (int i = 0; i < 8; i++) {
    long mrow = (long)rt * 256 + wr * 128 + i * 16 + sl * 4;
#pragma unroll
    for (int j = 0; j < 4; j++) {
      int n = ct * 256 + wc * 64 + j * 16 + lr;
#pragma unroll
      for (int r = 0; r < 4; r++)
        Qb[(mrow + r) * 1024 + n] = (__bf16)acc[i][j][r];
    }
  }
}

// ---------------------------------------------------------------------------
// gram64 v2: 20 cross-grams + lane-local softmax -> V. (r15, ~107.7us)
__global__ __launch_bounds__(512, 2) void gram64(
    const __bf16* __restrict__ Q, const __bf16* __restrict__ O, __bf16* __restrict__ V)
{
  __shared__ __align__(16) char ldsb[2 * 40960];  // 80 KB
  int bid = blockIdx.x;
  int xcd = bid & 7, idx = bid >> 3;   // 512 = 8 XCD x 64 (bijective)
  int b = xcd * 4 + (idx >> 4);        // 4 batches per XCD
  int rem = idx & 15;
  int s1t = rem >> 2, s2t = rem & 3;   // s1t-major within batch
  int t = threadIdx.x, l = t & 63, w = t >> 6;
  int wr = w >> 1, wc = w & 1;
  f32x4 acc[20][2] = {};

  const char* gp[5];
  int wdst[5];
#pragma unroll
  for (int p = 0; p < 5; p++) {
    int c = t + 512 * p;
    int isQ = c < 1280;
    int cc = isQ ? c : c - 1280;
    int m = cc >> 8, rr = (cc >> 2) & 63, slot = cc & 3;
    long row = (long)m * (BB * SS) + (long)b * SS + (isQ ? s1t : s2t) * 64 + rr;
    gp[p] = (const char*)((isQ ? Q : O) + row * HH + slot * 8);
    wdst[p] = (isQ ? 0 : 20480) + m * 4096 + rr * 64 + ((slot ^ ((rr >> 1) & 3)) << 4);
  }
  bf16x8 sreg[5];

#define LOADS                                                     \
  {                                                               \
    _Pragma("unroll") for (int p = 0; p < 5; p++) {               \
      sreg[p] = *(const bf16x8*)gp[p];                            \
      gp[p] += 64;                                                \
    }                                                             \
  }
#define WRITES(BUF)                                               \
  {                                                               \
    char* base = ldsb + (BUF) * 40960;                            \
    _Pragma("unroll") for (int p = 0; p < 5; p++)                 \
      *(bf16x8*)(base + wdst[p]) = sreg[p];                       \
  }

  int lr = l & 15, sl = l >> 4;
  int swz = (sl ^ ((lr >> 1) & 3)) * 16;
  int qoff = (wr * 16 + lr) * 64 + swz;
  int ooff0 = 20480 + (wc * 32 + lr) * 64 + swz;
  int ooff1 = ooff0 + 1024;

#define COMPUTE(BUF)                                                                   \
  {                                                                                    \
    const char* base = ldsb + (BUF) * 40960;                                           \
    bf16x8 qf[5], of[5];                                                               \
    _Pragma("unroll") for (int m = 0; m < 5; m++)                                      \
      qf[m] = *(const bf16x8*)(base + m * 4096 + qoff);                                \
    _Pragma("unroll") for (int m = 0; m < 5; m++)                                      \
      of[m] = *(const bf16x8*)(base + m * 4096 + ooff0);                               \
    __builtin_amdgcn_s_setprio(1);                                                     \
    _Pragma("unroll") for (int i = 0; i < 5; i++) {                                    \
      _Pragma("unroll") for (int n = 0; n < 5; n++) {                                  \
        if (n != i)                                                                    \
          acc[PAIR(i, n)][0] = __builtin_amdgcn_mfma_f32_16x16x32_bf16(                \
              qf[i], of[n], acc[PAIR(i, n)][0], 0, 0, 0);                              \
      }                                                                                \
    }                                                                                  \
    __builtin_amdgcn_s_setprio(0);                                                     \
    _Pragma("unroll") for (int m = 0; m < 5; m++)                                      \
      of[m] = *(const bf16x8*)(base + m * 4096 + ooff1);                               \
    __builtin_amdgcn_s_setprio(1);                                                     \
    _Pragma("unroll") for (int i = 0; i < 5; i++) {                                    \
      _Pragma("unroll") for (int n = 0; n < 5; n++) {                                  \
        if (n != i)                                                                    \
          acc[PAIR(i, n)][1] = __builtin_amdgcn_mfma_f32_16x16x32_bf16(                \
              qf[i], of[n], acc[PAIR(i, n)][1], 0, 0, 0);                              \
      }                                                                                \
    }                                                                                  \
    __builtin_amdgcn_s_setprio(0);                                                     \
  }

#define BODY(CUR, T)                                              \
  {                                                               \
    COMPUTE(CUR)                                                  \
    if ((T) < 31) {                                               \
      asm volatile("s_waitcnt vmcnt(0)" ::: "memory");            \
      WRITES((CUR) ^ 1)                                           \
      if ((T) < 30) { LOADS }                                     \
    }                                                             \
    asm volatile("s_waitcnt lgkmcnt(0)" ::: "memory");            \
    __builtin_amdgcn_s_barrier();                                 \
  }

  LOADS
  asm volatile("s_waitcnt vmcnt(0)" ::: "memory");
  WRITES(0)
  LOADS
  asm volatile("s_waitcnt lgkmcnt(0)" ::: "memory");
  __builtin_amdgcn_s_barrier();

  for (int it = 0; it < 16; it++) {
    BODY(0, 2 * it)
    BODY(1, 2 * it + 1)
  }
#undef BODY
#undef COMPUTE
#undef WRITES
#undef LOADS

  int s1b = s1t * 64 + wr * 16 + sl * 4;
  int s2b = s2t * 64 + wc * 32 + lr;
#pragma unroll
  for (int h = 0; h < 2; h++) {
#pragma unroll
    for (int r = 0; r < 4; r++) {
      float vacc[5] = {0.f, 0.f, 0.f, 0.f, 0.f};
#pragma unroll
      for (int i = 0; i < 5; i++) {
        float gg[5];
        float mx = -3.0e38f;
#pragma unroll
        for (int n = 0; n < 5; n++)
          if (n != i) { gg[n] = acc[PAIR(i, n)][h][r]; mx = fmaxf(mx, gg[n]); }
        float ee[5], ssum = 0.f;
#pragma unroll
        for (int n = 0; n < 5; n++)
          if (n != i) { ee[n] = __expf(gg[n] - mx); ssum += ee[n]; }
        float inv = 1.0f / ssum;
#pragma unroll
        for (int n = 0; n < 5; n++)
          if (n != i) vacc[n] += ee[n] * inv;
      }
      int s1 = s1b + r, s2 = s2b + h * 16;
#pragma unroll
      for (int n = 0; n < 5; n++)
        V[((long)(n * BB + b) * SS + s1) * SS + s2] = (__bf16)vacc[n];
    }
  }
}

// ---------------------------------------------------------------------------
// out = 0.5 * sum_n V_n @ o_n (per batch). A: V rows (bf16, s2-contig).
// B: Obf bf16 (s2 x h), transposed in LDS via 4x4 register sub-blocks.
__global__ __launch_bounds__(256) void pvgemm(
    const __bf16* __restrict__ Vb, const __bf16* __restrict__ Obf, float* __restrict__ out)
{
  __shared__ __bf16 smA[128][40];
  __shared__ __bf16 smB[128][40];
  int bid = blockIdx.x;
  int b = bid >> 4, s1t = (bid >> 3) & 1, ht = bid & 7;
  int t = threadIdx.x, l = t & 63, w = t >> 6;
  int wm = w >> 1, wn = w & 1;
  f32x4 acc[4][4] = {};
#pragma unroll
  for (int n = 0; n < 5; n++) {
    const __bf16* On = Obf + (long)n * BB * SS * HH;
    for (int st2 = 0; st2 < 8; st2++) {
      int s20 = st2 * 32;
#pragma unroll
      for (int p = 0; p < 2; p++) {
        int c = t + p * 256;
        int row = c >> 2, sl = c & 3;
        *(bf16x8*)&smA[row][sl * 8] =
            *(const bf16x8*)(Vb + (long)(n * BB + b) * SS * SS + (long)(s1t * 128 + row) * SS +
                             s20 + sl * 8);
      }
      {
        int h4 = (t & 31) * 4, s2q = (t >> 5) * 4;
        const __bf16* src = On + ((long)b * 256 + s20 + s2q) * 1024 + ht * 128 + h4;
        bf16x4 v0 = *(const bf16x4*)(src);
        bf16x4 v1 = *(const bf16x4*)(src + 1024);
        bf16x4 v2 = *(const bf16x4*)(src + 2048);
        bf16x4 v3 = *(const bf16x4*)(src + 3072);
        bf16x4 c0, c1, c2, c3;
        c0[0] = v0[0]; c0[1] = v1[0]; c0[2] = v2[0]; c0[3] = v3[0];
        c1[0] = v0[1]; c1[1] = v1[1]; c1[2] = v2[1]; c1[3] = v3[1];
        c2[0] = v0[2]; c2[1] = v1[2]; c2[2] = v2[2]; c2[3] = v3[2];
        c3[0] = v0[3]; c3[1] = v1[3]; c3[2] = v2[3]; c3[3] = v3[3];
        *(bf16x4*)&smB[h4 + 0][s2q] = c0;
        *(bf16x4*)&smB[h4 + 1][s2q] = c1;
        *(bf16x4*)&smB[h4 + 2][s2q] = c2;
        *(bf16x4*)&smB[h4 + 3][s2q] = c3;
      }
      __syncthreads();
      bf16x8 af[4], bfr[4];
      int sl = l >> 4, lr = l & 15;
#pragma unroll
      for (int i = 0; i < 4; i++) {
        af[i]  = *(const bf16x8*)&smA[wm * 64 + i * 16 + lr][sl * 8];
        bfr[i] = *(const bf16x8*)&smB[wn * 64 + i * 16 + lr][sl * 8];
      }
#pragma unroll
      for (int i = 0; i < 4; i++)
#pragma unroll
        for (int j = 0; j < 4; j++)
          acc[i][j] = __builtin_amdgcn_mfma_f32_16x16x32_bf16(af[i], bfr[j], acc[i][j], 0, 0, 0);
      __syncthreads();
    }
  }
#pragma unroll
  for (int i = 0; i < 4; i++) {
    int m = s1t * 128 + wm * 64 + i * 16 + ((l >> 4) << 2);
#pragma unroll
    for (int j = 0; j < 4; j++) {
      int n = ht * 128 + wn * 64 + j * 16 + (l & 15);
#pragma unroll
      for (int r = 0; r < 4; r++)
        out[(long)(b * SS + m + r) * HH + n] = 0.5f * acc[i][j][r];
    }
  }
}

// ---------------------------------------------------------------------------
extern "C" void kernel_launch(void* const* d_in, const int* in_sizes, int n_in,
                              void* d_out, int out_size, void* d_ws, size_t ws_size,
                              hipStream_t stream)
{
  const size_t SZ_W = (size_t)HH * HH * 2;           //  2 MB
  const size_t SZ_Q = (size_t)5 * BB * SS * HH * 2;  // 84 MB
  const size_t SZ_V = (size_t)5 * BB * SS * SS * 2;  // 21 MB
  const size_t SZ_O = (size_t)5 * BB * SS * HH * 2;  // 84 MB
  const size_t NEED = SZ_W + SZ_Q + SZ_V + SZ_O;     // 191 MB (proven available r4)
  if (ws_size < NEED) {
    canary<<<1, 1, 0, stream>>>((float*)d_out, (float)(ws_size >> 20));
    return;
  }
  char* ws = (char*)d_ws;
  __bf16* Wt  = (__bf16*)ws;
  __bf16* Qb  = (__bf16*)(ws + SZ_W);
  __bf16* Vb  = (__bf16*)(ws + SZ_W + SZ_Q);
  __bf16* Obf = (__bf16*)(ws + SZ_W + SZ_Q + SZ_V);
  const float* o0 = (const float*)d_in[0];
  const float* o1 = (const float*)d_in[1];
  const float* o2 = (const float*)d_in[2];
  const float* o3 = (const float*)d_in[3];
  const float* o4 = (const float*)d_in[4];

  cast_trW<<<256, 256, 0, stream>>>((const float*)d_in[5], Wt);
  qgemm_f32<<<640, 512, 0, stream>>>(o0, o1, o2, o3, o4, Wt, Qb, Obf);
  gram64<<<512, 512, 0, stream>>>(Qb, Obf, Vb);
  pvgemm<<<512, 256, 0, stream>>>(Vb, Obf, (float*)d_out);
}

// Round 18
// 270.298 us; speedup vs baseline: 1.0040x; 1.0040x over previous
//
#include <hip/hip_runtime.h>
#include <hip/hip_bf16.h>
#include <stdint.h>

// Problem: b=32, s=256, h=1024, 5 options.
// out = 0.5 * sum_n V_n @ o_n,  V_n = sum_{i!=n} softmax_k(q_i . o_k)_n,  q_i = o_i @ W
// bias is softmax-shift-invariant -> ignored.
// Round 18: r17 fusion reverted (fp32 re-read x4). Back to r14 split. qgemm
// retiled 128x256 -> grid 1280 = 5x256 CUs (100% pack vs 640 = 83%): removes
// the ~17% dispatch tail that capped every schedule variant at ~108us.
// Same r13/r14 proven schedule. gram64 v2 / pvgemm / casts frozen.

#define BB 32
#define SS 256
#define HH 1024

typedef __attribute__((ext_vector_type(4))) float f32x4;
typedef __attribute__((ext_vector_type(8))) __bf16 bf16x8;
typedef __attribute__((ext_vector_type(4))) __bf16 bf16x4;

__device__ constexpr int PAIR(int i, int n) { return i * 4 + (n > i ? n - 1 : n); }

__device__ __forceinline__ void gload_lds16(const void* g, void* l) {
  __builtin_amdgcn_global_load_lds((const __attribute__((address_space(1))) void*)g,
                                   (__attribute__((address_space(3))) void*)l, 16, 0, 0);
}

__global__ void canary(float* out, float v) { out[0] = v; }

// ---------------------------------------------------------------------------
// fp32 -> bf16 flat cast of the 5 options into Obf[m][b][s][h].
__global__ __launch_bounds__(256) void cast_all(
    const float* p0, const float* p1, const float* p2, const float* p3, const float* p4,
    __bf16* __restrict__ dst)
{
  int m = blockIdx.x >> 12;
  long off = ((long)(blockIdx.x & 4095) * 256 + threadIdx.x) * 8;
  const float* src = m == 0 ? p0 : m == 1 ? p1 : m == 2 ? p2 : m == 3 ? p3 : p4;
  float4 v0 = *(const float4*)(src + off);
  float4 v1 = *(const float4*)(src + off + 4);
  bf16x8 h;
  h[0] = (__bf16)v0.x; h[1] = (__bf16)v0.y; h[2] = (__bf16)v0.z; h[3] = (__bf16)v0.w;
  h[4] = (__bf16)v1.x; h[5] = (__bf16)v1.y; h[6] = (__bf16)v1.z; h[7] = (__bf16)v1.w;
  *(bf16x8*)(dst + (long)m * BB * SS * HH + off) = h;
}

// ---------------------------------------------------------------------------
// W (1024x1024 fp32) -> Wt (bf16, transposed). 64x64 tiles, grid 256.
__global__ __launch_bounds__(256) void cast_trW(const float* __restrict__ src,
                                                __bf16* __restrict__ dstT)
{
  __shared__ __bf16 tile[64][72];
  int ct = blockIdx.x & 15, rt = blockIdx.x >> 4;
  const float* s = src + (long)(rt * 64) * 1024 + ct * 64;
  int t = threadIdx.x;
#pragma unroll
  for (int p = 0; p < 4; p++) {
    int c = t + p * 256;
    int row = c >> 4, c4 = c & 15;
    float4 v = *(const float4*)(s + (long)row * 1024 + c4 * 4);
    bf16x4 h;
    h[0] = (__bf16)v.x; h[1] = (__bf16)v.y; h[2] = (__bf16)v.z; h[3] = (__bf16)v.w;
    *(bf16x4*)&tile[row][c4 * 4] = h;
  }
  __syncthreads();
#pragma unroll
  for (int p = 0; p < 4; p++) {
    int c = t + p * 256;
    int hr = c >> 4, s4 = c & 15;
    bf16x4 h;
    h[0] = tile[s4 * 4 + 0][hr];
    h[1] = tile[s4 * 4 + 1][hr];
    h[2] = tile[s4 * 4 + 2][hr];
    h[3] = tile[s4 * 4 + 3][hr];
    *(bf16x4*)(dstT + (long)(ct * 64 + hr) * 1024 + rt * 64 + s4 * 4) = h;
  }
}

// ---------------------------------------------------------------------------
// qgemm128: Q = Obf @ Wt. 128x256 tile, 512 thr, 8 waves (2x4; wave 64x64),
// BK=64, 2x48KB dbuf, one vmcnt(0)+barrier per K-tile, 8-slot XOR swizzle.
// Grid 1280 = 8 XCD x (40 rt x 4 ct) -> exactly 5 full CU rounds.
__global__ __launch_bounds__(512, 1) void qgemm128(
    const __bf16* __restrict__ A, const __bf16* __restrict__ Bt, __bf16* __restrict__ C)
{
  __shared__ __align__(16) char ldsb[2 * 49152];  // per buf: A[16K] B[32K]
  int lin = blockIdx.x;
  int xcd = lin & 7, idx = lin >> 3;         // 1280 = 8 x 160 (bijective)
  int rt = xcd * 40 + (idx >> 2), ct = idx & 3;
  int t = threadIdx.x, l = t & 63, w = t >> 6;
  int wr = w >> 2, wc = w & 3;               // wave patch: 64 x 64
  f32x4 acc[4][4] = {};

  // A: 128x64 = 1024 chunks (2/thread); B: 256x64 = 2048 chunks (4/thread).
  // chunk c: row=c>>3, slot=c&7; source slot pre-swizzled slot^(row&7);
  // LDS dest linear (wave-uniform base; HW adds lane*16).
  const char* gA[2];
  int dA[2];
#pragma unroll
  for (int p = 0; p < 2; p++) {
    int c = t + 512 * p;
    int row = c >> 3;
    int sg = (c & 7) ^ (row & 7);
    gA[p] = (const char*)(A + (long)(rt * 128 + row) * 1024 + sg * 8);
    dA[p] = ((t & ~63) + 512 * p) * 16;
  }
  const char* gB[4];
  int dB[4];
#pragma unroll
  for (int p = 0; p < 4; p++) {
    int c = t + 512 * p;
    int row = c >> 3;
    int sg = (c & 7) ^ (row & 7);
    gB[p] = (const char*)(Bt + (long)(ct * 256 + row) * 1024 + sg * 8);
    dB[p] = 16384 + ((t & ~63) + 512 * p) * 16;
  }

  int lr = l & 15, sl = l >> 4;
  int sx0 = (sl ^ (lr & 7)) * 16;        // k-half 0
  int sx1 = ((4 | sl) ^ (lr & 7)) * 16;  // k-half 1
  int arow = (wr * 64 + lr) * 128;             // + i*2048
  int brow = 16384 + (wc * 64 + lr) * 128;     // + j*2048

#define TILE(CUR, DOSTAGE)                                                             \
  {                                                                                    \
    const char* base = ldsb + (CUR) * 49152;                                           \
    char* sbase = ldsb + ((CUR) ^ 1) * 49152;                                          \
    bf16x8 bfr[4][2], af[2];                                                           \
    _Pragma("unroll") for (int j = 0; j < 4; j++) {                                    \
      bfr[j][0] = *(const bf16x8*)(base + brow + j * 2048 + sx0);                      \
      bfr[j][1] = *(const bf16x8*)(base + brow + j * 2048 + sx1);                      \
    }                                                                                  \
    _Pragma("unroll") for (int ph = 0; ph < 4; ph++) {                                 \
      if (DOSTAGE) {                                                                   \
        if (ph == 0) {                                                                 \
          gload_lds16(gA[0], sbase + dA[0]); gA[0] += 128;                             \
          gload_lds16(gA[1], sbase + dA[1]); gA[1] += 128;                             \
        } else if (ph == 1) {                                                          \
          gload_lds16(gB[0], sbase + dB[0]); gB[0] += 128;                             \
          gload_lds16(gB[1], sbase + dB[1]); gB[1] += 128;                             \
        } else if (ph == 2) {                                                          \
          gload_lds16(gB[2], sbase + dB[2]); gB[2] += 128;                             \
        } else {                                                                       \
          gload_lds16(gB[3], sbase + dB[3]); gB[3] += 128;                             \
        }                                                                              \
      }                                                                                \
      af[0] = *(const bf16x8*)(base + arow + ph * 2048 + sx0);                         \
      af[1] = *(const bf16x8*)(base + arow + ph * 2048 + sx1);                         \
      __builtin_amdgcn_s_setprio(1);                                                   \
      _Pragma("unroll") for (int j = 0; j < 4; j++) {                                  \
        acc[ph][j] = __builtin_amdgcn_mfma_f32_16x16x32_bf16(                          \
            af[0], bfr[j][0], acc[ph][j], 0, 0, 0);                                    \
        acc[ph][j] = __builtin_amdgcn_mfma_f32_16x16x32_bf16(                          \
            af[1], bfr[j][1], acc[ph][j], 0, 0, 0);                                    \
      }                                                                                \
      __builtin_amdgcn_s_setprio(0);                                                   \
    }                                                                                  \
  }

  // prologue: stage tile 0 into buf0
  {
#pragma unroll
    for (int p = 0; p < 2; p++) { gload_lds16(gA[p], ldsb + dA[p]); gA[p] += 128; }
#pragma unroll
    for (int p = 0; p < 4; p++) { gload_lds16(gB[p], ldsb + dB[p]); gB[p] += 128; }
  }
  asm volatile("s_waitcnt vmcnt(0)" ::: "memory");
  __builtin_amdgcn_s_barrier();
  for (int tt = 0; tt < 15; tt++) {  // tiles 0..14, staging 1..15
    TILE(tt & 1, 1)
    asm volatile("s_waitcnt vmcnt(0)" ::: "memory");
    __builtin_amdgcn_s_barrier();
  }
  TILE(1, 0)  // tile 15
#undef TILE

#pragma unroll
  for (int i = 0; i < 4; i++) {
    long mrow = (long)rt * 128 + wr * 64 + i * 16 + sl * 4;
#pragma unroll
    for (int j = 0; j < 4; j++) {
      int n = ct * 256 + wc * 64 + j * 16 + lr;
#pragma unroll
      for (int r = 0; r < 4; r++)
        C[(mrow + r) * 1024 + n] = (__bf16)acc[i][j][r];
    }
  }
}

// ---------------------------------------------------------------------------
// gram64 v2: 20 cross-grams + lane-local softmax -> V. (r15-r17, ~108us)
__global__ __launch_bounds__(512, 2) void gram64(
    const __bf16* __restrict__ Q, const __bf16* __restrict__ O, __bf16* __restrict__ V)
{
  __shared__ __align__(16) char ldsb[2 * 40960];  // 80 KB
  int bid = blockIdx.x;
  int xcd = bid & 7, idx = bid >> 3;   // 512 = 8 XCD x 64 (bijective)
  int b = xcd * 4 + (idx >> 4);        // 4 batches per XCD
  int rem = idx & 15;
  int s1t = rem >> 2, s2t = rem & 3;   // s1t-major within batch
  int t = threadIdx.x, l = t & 63, w = t >> 6;
  int wr = w >> 1, wc = w & 1;
  f32x4 acc[20][2] = {};

  const char* gp[5];
  int wdst[5];
#pragma unroll
  for (int p = 0; p < 5; p++) {
    int c = t + 512 * p;
    int isQ = c < 1280;
    int cc = isQ ? c : c - 1280;
    int m = cc >> 8, rr = (cc >> 2) & 63, slot = cc & 3;
    long row = (long)m * (BB * SS) + (long)b * SS + (isQ ? s1t : s2t) * 64 + rr;
    gp[p] = (const char*)((isQ ? Q : O) + row * HH + slot * 8);
    wdst[p] = (isQ ? 0 : 20480) + m * 4096 + rr * 64 + ((slot ^ ((rr >> 1) & 3)) << 4);
  }
  bf16x8 sreg[5];

#define LOADS                                                     \
  {                                                               \
    _Pragma("unroll") for (int p = 0; p < 5; p++) {               \
      sreg[p] = *(const bf16x8*)gp[p];                            \
      gp[p] += 64;                                                \
    }                                                             \
  }
#define WRITES(BUF)                                               \
  {                                                               \
    char* base = ldsb + (BUF) * 40960;                            \
    _Pragma("unroll") for (int p = 0; p < 5; p++)                 \
      *(bf16x8*)(base + wdst[p]) = sreg[p];                       \
  }

  int lr = l & 15, sl = l >> 4;
  int swz = (sl ^ ((lr >> 1) & 3)) * 16;
  int qoff = (wr * 16 + lr) * 64 + swz;
  int ooff0 = 20480 + (wc * 32 + lr) * 64 + swz;
  int ooff1 = ooff0 + 1024;

#define COMPUTE(BUF)                                                                   \
  {                                                                                    \
    const char* base = ldsb + (BUF) * 40960;                                           \
    bf16x8 qf[5], of[5];                                                               \
    _Pragma("unroll") for (int m = 0; m < 5; m++)                                      \
      qf[m] = *(const bf16x8*)(base + m * 4096 + qoff);                                \
    _Pragma("unroll") for (int m = 0; m < 5; m++)                                      \
      of[m] = *(const bf16x8*)(base + m * 4096 + ooff0);                               \
    __builtin_amdgcn_s_setprio(1);                                                     \
    _Pragma("unroll") for (int i = 0; i < 5; i++) {                                    \
      _Pragma("unroll") for (int n = 0; n < 5; n++) {                                  \
        if (n != i)                                                                    \
          acc[PAIR(i, n)][0] = __builtin_amdgcn_mfma_f32_16x16x32_bf16(                \
              qf[i], of[n], acc[PAIR(i, n)][0], 0, 0, 0);                              \
      }                                                                                \
    }                                                                                  \
    __builtin_amdgcn_s_setprio(0);                                                     \
    _Pragma("unroll") for (int m = 0; m < 5; m++)                                      \
      of[m] = *(const bf16x8*)(base + m * 4096 + ooff1);                               \
    __builtin_amdgcn_s_setprio(1);                                                     \
    _Pragma("unroll") for (int i = 0; i < 5; i++) {                                    \
      _Pragma("unroll") for (int n = 0; n < 5; n++) {                                  \
        if (n != i)                                                                    \
          acc[PAIR(i, n)][1] = __builtin_amdgcn_mfma_f32_16x16x32_bf16(                \
              qf[i], of[n], acc[PAIR(i, n)][1], 0, 0, 0);                              \
      }                                                                                \
    }                                                                                  \
    __builtin_amdgcn_s_setprio(0);                                                     \
  }

#define BODY(CUR, T)                                              \
  {                                                               \
    COMPUTE(CUR)                                                  \
    if ((T) < 31) {                                               \
      asm volatile("s_waitcnt vmcnt(0)" ::: "memory");            \
      WRITES((CUR) ^ 1)                                           \
      if ((T) < 30) { LOADS }                                     \
    }                                                             \
    asm volatile("s_waitcnt lgkmcnt(0)" ::: "memory");            \
    __builtin_amdgcn_s_barrier();                                 \
  }

  LOADS
  asm volatile("s_waitcnt vmcnt(0)" ::: "memory");
  WRITES(0)
  LOADS
  asm volatile("s_waitcnt lgkmcnt(0)" ::: "memory");
  __builtin_amdgcn_s_barrier();

  for (int it = 0; it < 16; it++) {
    BODY(0, 2 * it)
    BODY(1, 2 * it + 1)
  }
#undef BODY
#undef COMPUTE
#undef WRITES
#undef LOADS

  int s1b = s1t * 64 + wr * 16 + sl * 4;
  int s2b = s2t * 64 + wc * 32 + lr;
#pragma unroll
  for (int h = 0; h < 2; h++) {
#pragma unroll
    for (int r = 0; r < 4; r++) {
      float vacc[5] = {0.f, 0.f, 0.f, 0.f, 0.f};
#pragma unroll
      for (int i = 0; i < 5; i++) {
        float gg[5];
        float mx = -3.0e38f;
#pragma unroll
        for (int n = 0; n < 5; n++)
          if (n != i) { gg[n] = acc[PAIR(i, n)][h][r]; mx = fmaxf(mx, gg[n]); }
        float ee[5], ssum = 0.f;
#pragma unroll
        for (int n = 0; n < 5; n++)
          if (n != i) { ee[n] = __expf(gg[n] - mx); ssum += ee[n]; }
        float inv = 1.0f / ssum;
#pragma unroll
        for (int n = 0; n < 5; n++)
          if (n != i) vacc[n] += ee[n] * inv;
      }
      int s1 = s1b + r, s2 = s2b + h * 16;
#pragma unroll
      for (int n = 0; n < 5; n++)
        V[((long)(n * BB + b) * SS + s1) * SS + s2] = (__bf16)vacc[n];
    }
  }
}

// ---------------------------------------------------------------------------
// out = 0.5 * sum_n V_n @ o_n (per batch). A: V rows (bf16, s2-contig).
// B: Obf bf16 (s2 x h), transposed in LDS via 4x4 register sub-blocks.
__global__ __launch_bounds__(256) void pvgemm(
    const __bf16* __restrict__ Vb, const __bf16* __restrict__ Obf, float* __restrict__ out)
{
  __shared__ __bf16 smA[128][40];
  __shared__ __bf16 smB[128][40];
  int bid = blockIdx.x;
  int b = bid >> 4, s1t = (bid >> 3) & 1, ht = bid & 7;
  int t = threadIdx.x, l = t & 63, w = t >> 6;
  int wm = w >> 1, wn = w & 1;
  f32x4 acc[4][4] = {};
#pragma unroll
  for (int n = 0; n < 5; n++) {
    const __bf16* On = Obf + (long)n * BB * SS * HH;
    for (int st2 = 0; st2 < 8; st2++) {
      int s20 = st2 * 32;
#pragma unroll
      for (int p = 0; p < 2; p++) {
        int c = t + p * 256;
        int row = c >> 2, sl = c & 3;
        *(bf16x8*)&smA[row][sl * 8] =
            *(const bf16x8*)(Vb + (long)(n * BB + b) * SS * SS + (long)(s1t * 128 + row) * SS +
                             s20 + sl * 8);
      }
      {
        int h4 = (t & 31) * 4, s2q = (t >> 5) * 4;
        const __bf16* src = On + ((long)b * 256 + s20 + s2q) * 1024 + ht * 128 + h4;
        bf16x4 v0 = *(const bf16x4*)(src);
        bf16x4 v1 = *(const bf16x4*)(src + 1024);
        bf16x4 v2 = *(const bf16x4*)(src + 2048);
        bf16x4 v3 = *(const bf16x4*)(src + 3072);
        bf16x4 c0, c1, c2, c3;
        c0[0] = v0[0]; c0[1] = v1[0]; c0[2] = v2[0]; c0[3] = v3[0];
        c1[0] = v0[1]; c1[1] = v1[1]; c1[2] = v2[1]; c1[3] = v3[1];
        c2[0] = v0[2]; c2[1] = v1[2]; c2[2] = v2[2]; c2[3] = v3[2];
        c3[0] = v0[3]; c3[1] = v1[3]; c3[2] = v2[3]; c3[3] = v3[3];
        *(bf16x4*)&smB[h4 + 0][s2q] = c0;
        *(bf16x4*)&smB[h4 + 1][s2q] = c1;
        *(bf16x4*)&smB[h4 + 2][s2q] = c2;
        *(bf16x4*)&smB[h4 + 3][s2q] = c3;
      }
      __syncthreads();
      bf16x8 af[4], bfr[4];
      int sl = l >> 4, lr = l & 15;
#pragma unroll
      for (int i = 0; i < 4; i++) {
        af[i]  = *(const bf16x8*)&smA[wm * 64 + i * 16 + lr][sl * 8];
        bfr[i] = *(const bf16x8*)&smB[wn * 64 + i * 16 + lr][sl * 8];
      }
#pragma unroll
      for (int i = 0; i < 4; i++)
#pragma unroll
        for (int j = 0; j < 4; j++)
          acc[i][j] = __builtin_amdgcn_mfma_f32_16x16x32_bf16(af[i], bfr[j], acc[i][j], 0, 0, 0);
      __syncthreads();
    }
  }
#pragma unroll
  for (int i = 0; i < 4; i++) {
    int m = s1t * 128 + wm * 64 + i * 16 + ((l >> 4) << 2);
#pragma unroll
    for (int j = 0; j < 4; j++) {
      int n = ht * 128 + wn * 64 + j * 16 + (l & 15);
#pragma unroll
      for (int r = 0; r < 4; r++)
        out[(long)(b * SS + m + r) * HH + n] = 0.5f * acc[i][j][r];
    }
  }
}

// ---------------------------------------------------------------------------
extern "C" void kernel_launch(void* const* d_in, const int* in_sizes, int n_in,
                              void* d_out, int out_size, void* d_ws, size_t ws_size,
                              hipStream_t stream)
{
  const size_t SZ_W = (size_t)HH * HH * 2;           //  2 MB
  const size_t SZ_Q = (size_t)5 * BB * SS * HH * 2;  // 84 MB
  const size_t SZ_V = (size_t)5 * BB * SS * SS * 2;  // 21 MB
  const size_t SZ_O = (size_t)5 * BB * SS * HH * 2;  // 84 MB
  const size_t NEED = SZ_W + SZ_Q + SZ_V + SZ_O;     // 191 MB (proven available r4)
  if (ws_size < NEED) {
    canary<<<1, 1, 0, stream>>>((float*)d_out, (float)(ws_size >> 20));
    return;
  }
  char* ws = (char*)d_ws;
  __bf16* Wt  = (__bf16*)ws;
  __bf16* Qb  = (__bf16*)(ws + SZ_W);
  __bf16* Vb  = (__bf16*)(ws + SZ_W + SZ_Q);
  __bf16* Obf = (__bf16*)(ws + SZ_W + SZ_Q + SZ_V);
  const float* o0 = (const float*)d_in[0];
  const float* o1 = (const float*)d_in[1];
  const float* o2 = (const float*)d_in[2];
  const float* o3 = (const float*)d_in[3];
  const float* o4 = (const float*)d_in[4];

  cast_trW<<<256, 256, 0, stream>>>((const float*)d_in[5], Wt);
  cast_all<<<5 * 4096, 256, 0, stream>>>(o0, o1, o2, o3, o4, Obf);
  qgemm128<<<1280, 512, 0, stream>>>(Obf, Wt, Qb);
  gram64<<<512, 512, 0, stream>>>(Qb, Obf, Vb);
  pvgemm<<<512, 256, 0, stream>>>(Vb, Obf, (float*)d_out);
}

// Round 19
// 263.115 us; speedup vs baseline: 1.0314x; 1.0273x over previous
//
#include <hip/hip_runtime.h>
#include <hip/hip_bf16.h>
#include <stdint.h>

// Problem: b=32, s=256, h=1024, 5 options.
// out = 0.5 * sum_n V_n @ o_n,  V_n = sum_{i!=n} softmax_k(q_i . o_k)_n,  q_i = o_i @ W
// bias is softmax-shift-invariant -> ignored.
// Round 19: exact revert to round-14 best (262.06us): qgemm256 (BK=64, 2x64KB
// dbuf, one vmcnt(0)+barrier/tile, 8-slot XOR swizzle, 2 blocks/CU) +
// gram64 (16x32 wave patches, r8 3-buffer vmcnt(5) protocol) + pvgemm + casts.
// 17 structural variants on the MFMA kernels all bound at ~108us each;
// fusion (r17) and grid-packing (r18) regressed. This is the composed optimum.

#define BB 32
#define SS 256
#define HH 1024

typedef __attribute__((ext_vector_type(4))) float f32x4;
typedef __attribute__((ext_vector_type(8))) __bf16 bf16x8;
typedef __attribute__((ext_vector_type(4))) __bf16 bf16x4;

__device__ constexpr int PAIR(int i, int n) { return i * 4 + (n > i ? n - 1 : n); }

__device__ __forceinline__ void gload_lds16(const void* g, void* l) {
  __builtin_amdgcn_global_load_lds((const __attribute__((address_space(1))) void*)g,
                                   (__attribute__((address_space(3))) void*)l, 16, 0, 0);
}

__global__ void canary(float* out, float v) { out[0] = v; }

// ---------------------------------------------------------------------------
// fp32 -> bf16 flat cast of the 5 options into Obf[m][b][s][h].
__global__ __launch_bounds__(256) void cast_all(
    const float* p0, const float* p1, const float* p2, const float* p3, const float* p4,
    __bf16* __restrict__ dst)
{
  int m = blockIdx.x >> 12;
  long off = ((long)(blockIdx.x & 4095) * 256 + threadIdx.x) * 8;
  const float* src = m == 0 ? p0 : m == 1 ? p1 : m == 2 ? p2 : m == 3 ? p3 : p4;
  float4 v0 = *(const float4*)(src + off);
  float4 v1 = *(const float4*)(src + off + 4);
  bf16x8 h;
  h[0] = (__bf16)v0.x; h[1] = (__bf16)v0.y; h[2] = (__bf16)v0.z; h[3] = (__bf16)v0.w;
  h[4] = (__bf16)v1.x; h[5] = (__bf16)v1.y; h[6] = (__bf16)v1.z; h[7] = (__bf16)v1.w;
  *(bf16x8*)(dst + (long)m * BB * SS * HH + off) = h;
}

// ---------------------------------------------------------------------------
// W (1024x1024 fp32) -> Wt (bf16, transposed). 64x64 tiles, grid 256.
__global__ __launch_bounds__(256) void cast_trW(const float* __restrict__ src,
                                                __bf16* __restrict__ dstT)
{
  __shared__ __bf16 tile[64][72];
  int ct = blockIdx.x & 15, rt = blockIdx.x >> 4;
  const float* s = src + (long)(rt * 64) * 1024 + ct * 64;
  int t = threadIdx.x;
#pragma unroll
  for (int p = 0; p < 4; p++) {
    int c = t + p * 256;
    int row = c >> 4, c4 = c & 15;
    float4 v = *(const float4*)(s + (long)row * 1024 + c4 * 4);
    bf16x4 h;
    h[0] = (__bf16)v.x; h[1] = (__bf16)v.y; h[2] = (__bf16)v.z; h[3] = (__bf16)v.w;
    *(bf16x4*)&tile[row][c4 * 4] = h;
  }
  __syncthreads();
#pragma unroll
  for (int p = 0; p < 4; p++) {
    int c = t + p * 256;
    int hr = c >> 4, s4 = c & 15;
    bf16x4 h;
    h[0] = tile[s4 * 4 + 0][hr];
    h[1] = tile[s4 * 4 + 1][hr];
    h[2] = tile[s4 * 4 + 2][hr];
    h[3] = tile[s4 * 4 + 3][hr];
    *(bf16x4*)(dstT + (long)(ct * 64 + hr) * 1024 + rt * 64 + s4 * 4) = h;
  }
}

// ---------------------------------------------------------------------------
// qgemm256: Q = Obf @ Wt. 256x256 tile, 512 thr, 8 waves, BK=64, 2x64KB dbuf,
// 4-phase interleave, one vmcnt(0)+barrier per tile. (r13/r14, proven)
__global__ __launch_bounds__(512, 2) void qgemm256(
    const __bf16* __restrict__ A, const __bf16* __restrict__ Bt, __bf16* __restrict__ C)
{
  __shared__ __align__(16) char ldsb[2 * 65536];
  int lin = blockIdx.x;
  int xcd = lin & 7, idx = lin >> 3;
  int rt = xcd * 20 + (idx >> 2), ct = idx & 3;
  int t = threadIdx.x, l = t & 63, w = t >> 6;
  int wr = w >> 2, wc = w & 3;
  f32x4 acc[8][4] = {};

  const char* gp[8];
  int dstp[8];
#pragma unroll
  for (int p = 0; p < 8; p++) {
    int c = t + 512 * (p & 3);
    int row = c >> 3;
    int sg = (c & 7) ^ (row & 7);
    if (p < 4) {
      gp[p] = (const char*)(A + (long)(rt * 256 + row) * 1024 + sg * 8);
      dstp[p] = w * 1024 + (p & 3) * 8192;
    } else {
      gp[p] = (const char*)(Bt + (long)(ct * 256 + row) * 1024 + sg * 8);
      dstp[p] = 32768 + w * 1024 + (p & 3) * 8192;
    }
  }

  int lr = l & 15, sl = l >> 4;
  int sx0 = (sl ^ (lr & 7)) * 16;
  int sx1 = ((4 | sl) ^ (lr & 7)) * 16;
  int arow = (wr * 128 + lr) * 128;
  int brow = 32768 + (wc * 64 + lr) * 128;

#define TILE(CUR, DOSTAGE)                                                             \
  {                                                                                    \
    const char* base = ldsb + (CUR) * 65536;                                           \
    char* sbase = ldsb + ((CUR) ^ 1) * 65536;                                          \
    bf16x8 bfr[4][2], af[2][2];                                                        \
    _Pragma("unroll") for (int j = 0; j < 4; j++) {                                    \
      bfr[j][0] = *(const bf16x8*)(base + brow + j * 2048 + sx0);                      \
      bfr[j][1] = *(const bf16x8*)(base + brow + j * 2048 + sx1);                      \
    }                                                                                  \
    _Pragma("unroll") for (int ph = 0; ph < 4; ph++) {                                 \
      if (DOSTAGE) {                                                                   \
        gload_lds16(gp[ph], sbase + dstp[ph]);                                         \
        gload_lds16(gp[ph + 4], sbase + dstp[ph + 4]);                                 \
      }                                                                                \
      _Pragma("unroll") for (int ii = 0; ii < 2; ii++) {                               \
        int i = ph * 2 + ii;                                                           \
        af[ii][0] = *(const bf16x8*)(base + arow + i * 2048 + sx0);                    \
        af[ii][1] = *(const bf16x8*)(base + arow + i * 2048 + sx1);                    \
      }                                                                                \
      __builtin_amdgcn_s_setprio(1);                                                   \
      _Pragma("unroll") for (int ii = 0; ii < 2; ii++)                                 \
        _Pragma("unroll") for (int j = 0; j < 4; j++) {                                \
          acc[ph * 2 + ii][j] = __builtin_amdgcn_mfma_f32_16x16x32_bf16(               \
              af[ii][0], bfr[j][0], acc[ph * 2 + ii][j], 0, 0, 0);                     \
          acc[ph * 2 + ii][j] = __builtin_amdgcn_mfma_f32_16x16x32_bf16(               \
              af[ii][1], bfr[j][1], acc[ph * 2 + ii][j], 0, 0, 0);                     \
        }                                                                              \
      __builtin_amdgcn_s_setprio(0);                                                   \
    }                                                                                  \
    if (DOSTAGE) {                                                                     \
      _Pragma("unroll") for (int p = 0; p < 8; p++) gp[p] += 128;                      \
    }                                                                                  \
  }

  {
#pragma unroll
    for (int p = 0; p < 8; p++) {
      gload_lds16(gp[p], ldsb + dstp[p]);
      gp[p] += 128;
    }
  }
  asm volatile("s_waitcnt vmcnt(0)" ::: "memory");
  __builtin_amdgcn_s_barrier();
  for (int tt = 0; tt < 15; tt++) {
    TILE(tt & 1, 1)
    asm volatile("s_waitcnt vmcnt(0)" ::: "memory");
    __builtin_amdgcn_s_barrier();
  }
  TILE(1, 0)
#undef TILE

#pragma unroll
  for (int i = 0; i < 8; i++) {
    long mrow = (long)rt * 256 + wr * 128 + i * 16 + (sl << 2);
#pragma unroll
    for (int j = 0; j < 4; j++) {
      int n = ct * 256 + wc * 64 + j * 16 + lr;
#pragma unroll
      for (int r = 0; r < 4; r++)
        C[(mrow + r) * 1024 + n] = (__bf16)acc[i][j][r];
    }
  }
}

// ---------------------------------------------------------------------------
// gram64: 20 cross-grams + lane-local softmax -> V.
// 512 thr, 8 waves (4x2); wave patch 16(s1) x 32(s2); block 64x64.
// r8 staging protocol: 5 uniform DMA/thread, 3 buffers, vmcnt(5), one
// barrier/step, XOR swizzle both sides. (r14, proven 107.7us)
__global__ __launch_bounds__(512, 2) void gram64(
    const __bf16* __restrict__ Q, const __bf16* __restrict__ O, __bf16* __restrict__ V)
{
  __shared__ __align__(16) char ldsb[3 * 40960];  // 120 KB
  int bid = blockIdx.x;
  int xcd = bid & 7, idx = bid >> 3;   // 512 = 8 XCD x 64 (bijective)
  int b = xcd * 4 + (idx >> 4);        // 4 batches per XCD
  int rem = idx & 15;
  int s1t = rem >> 2, s2t = rem & 3;   // s1t-major within batch
  int t = threadIdx.x, l = t & 63, w = t >> 6;
  int wr = w >> 1, wc = w & 1;         // wave = s1 [wr*16,+16) x s2 [wc*32,+32)
  f32x4 acc[20][2] = {};               // [pair][s2-half]

  const char* gp[5];
#pragma unroll
  for (int p = 0; p < 5; p++) {
    int c = t + 512 * p;
    int isQ = c < 1280;
    int cc = isQ ? c : c - 1280;
    int m = cc >> 8, rr = (cc >> 2) & 63;
    int sg = (cc & 3) ^ ((cc >> 3) & 3);
    long row = (long)m * (BB * SS) + (long)b * SS + (isQ ? s1t : s2t) * 64 + rr;
    gp[p] = (const char*)((isQ ? Q : O) + row * HH + sg * 8);
  }
  int dstb = (t & ~63) << 4;  // wave-uniform; chunk p at +p*8192; HW adds lane*16

#define STAGE(BUF)                                                      \
  {                                                                     \
    char* base = ldsb + (BUF) * 40960 + dstb;                           \
    _Pragma("unroll") for (int p = 0; p < 5; p++) {                     \
      gload_lds16(gp[p], base + p * 8192);                              \
      gp[p] += 64;                                                      \
    }                                                                   \
  }

  int lr = l & 15, sl = l >> 4;
  int swz = (sl ^ ((lr >> 1) & 3)) * 16;
  int qoff = (wr * 16 + lr) * 64 + swz;
  int ooff0 = 20480 + (wc * 32 + lr) * 64 + swz;
  int ooff1 = ooff0 + 1024;  // +16 rows

#define COMPUTE(BUF)                                                                   \
  {                                                                                    \
    const char* base = ldsb + (BUF) * 40960;                                           \
    bf16x8 qf[5], of[5];                                                               \
    _Pragma("unroll") for (int m = 0; m < 5; m++)                                      \
      qf[m] = *(const bf16x8*)(base + m * 4096 + qoff);                                \
    _Pragma("unroll") for (int m = 0; m < 5; m++)                                      \
      of[m] = *(const bf16x8*)(base + m * 4096 + ooff0);                               \
    __builtin_amdgcn_s_setprio(1);                                                     \
    _Pragma("unroll") for (int i = 0; i < 5; i++) {                                    \
      _Pragma("unroll") for (int n = 0; n < 5; n++) {                                  \
        if (n != i)                                                                    \
          acc[PAIR(i, n)][0] = __builtin_amdgcn_mfma_f32_16x16x32_bf16(                \
              qf[i], of[n], acc[PAIR(i, n)][0], 0, 0, 0);                              \
      }                                                                                \
    }                                                                                  \
    __builtin_amdgcn_s_setprio(0);                                                     \
    _Pragma("unroll") for (int m = 0; m < 5; m++)                                      \
      of[m] = *(const bf16x8*)(base + m * 4096 + ooff1);                               \
    __builtin_amdgcn_s_setprio(1);                                                     \
    _Pragma("unroll") for (int i = 0; i < 5; i++) {                                    \
      _Pragma("unroll") for (int n = 0; n < 5; n++) {                                  \
        if (n != i)                                                                    \
          acc[PAIR(i, n)][1] = __builtin_amdgcn_mfma_f32_16x16x32_bf16(                \
              qf[i], of[n], acc[PAIR(i, n)][1], 0, 0, 0);                              \
      }                                                                                \
    }                                                                                  \
    __builtin_amdgcn_s_setprio(0);                                                     \
  }

#define STEP(CUR, STG)                                          \
  asm volatile("s_waitcnt vmcnt(5)" ::: "memory");              \
  __builtin_amdgcn_s_barrier();                                 \
  STAGE(STG);                                                   \
  COMPUTE(CUR);

  STAGE(0)
  STAGE(1)
  for (int it = 0; it < 10; it++) {  // K32-steps 0..29, staging 2..31
    STEP(0, 2)
    STEP(1, 0)
    STEP(2, 1)
  }
  asm volatile("s_waitcnt vmcnt(5)" ::: "memory");  // step 30
  __builtin_amdgcn_s_barrier();
  COMPUTE(0)
  asm volatile("s_waitcnt vmcnt(0)" ::: "memory");  // step 31
  __builtin_amdgcn_s_barrier();
  COMPUTE(1)
#undef STEP
#undef COMPUTE
#undef STAGE

  // epilogue: lane-local softmax over 4 options; C layout: s2 = l&15 (col),
  // s1 = (l>>4)*4 + r (row).
  int s1b = s1t * 64 + wr * 16 + sl * 4;
  int s2b = s2t * 64 + wc * 32 + lr;
#pragma unroll
  for (int h = 0; h < 2; h++) {
#pragma unroll
    for (int r = 0; r < 4; r++) {
      float vacc[5] = {0.f, 0.f, 0.f, 0.f, 0.f};
#pragma unroll
      for (int i = 0; i < 5; i++) {
        float gg[5];
        float mx = -3.0e38f;
#pragma unroll
        for (int n = 0; n < 5; n++)
          if (n != i) { gg[n] = acc[PAIR(i, n)][h][r]; mx = fmaxf(mx, gg[n]); }
        float ee[5], ssum = 0.f;
#pragma unroll
        for (int n = 0; n < 5; n++)
          if (n != i) { ee[n] = __expf(gg[n] - mx); ssum += ee[n]; }
        float inv = 1.0f / ssum;
#pragma unroll
        for (int n = 0; n < 5; n++)
          if (n != i) vacc[n] += ee[n] * inv;
      }
      int s1 = s1b + r, s2 = s2b + h * 16;
#pragma unroll
      for (int n = 0; n < 5; n++)
        V[((long)(n * BB + b) * SS + s1) * SS + s2] = (__bf16)vacc[n];
    }
  }
}

// ---------------------------------------------------------------------------
// out = 0.5 * sum_n V_n @ o_n (per batch). A: V rows (bf16, s2-contig).
// B: Obf bf16 (s2 x h), transposed in LDS via 4x4 register sub-blocks.
__global__ __launch_bounds__(256) void pvgemm(
    const __bf16* __restrict__ Vb, const __bf16* __restrict__ Obf, float* __restrict__ out)
{
  __shared__ __bf16 smA[128][40];
  __shared__ __bf16 smB[128][40];
  int bid = blockIdx.x;
  int b = bid >> 4, s1t = (bid >> 3) & 1, ht = bid & 7;
  int t = threadIdx.x, l = t & 63, w = t >> 6;
  int wm = w >> 1, wn = w & 1;
  f32x4 acc[4][4] = {};
#pragma unroll
  for (int n = 0; n < 5; n++) {
    const __bf16* On = Obf + (long)n * BB * SS * HH;
    for (int st2 = 0; st2 < 8; st2++) {
      int s20 = st2 * 32;
#pragma unroll
      for (int p = 0; p < 2; p++) {
        int c = t + p * 256;
        int row = c >> 2, sl = c & 3;
        *(bf16x8*)&smA[row][sl * 8] =
            *(const bf16x8*)(Vb + (long)(n * BB + b) * SS * SS + (long)(s1t * 128 + row) * SS +
                             s20 + sl * 8);
      }
      {
        int h4 = (t & 31) * 4, s2q = (t >> 5) * 4;
        const __bf16* src = On + ((long)b * 256 + s20 + s2q) * 1024 + ht * 128 + h4;
        bf16x4 v0 = *(const bf16x4*)(src);
        bf16x4 v1 = *(const bf16x4*)(src + 1024);
        bf16x4 v2 = *(const bf16x4*)(src + 2048);
        bf16x4 v3 = *(const bf16x4*)(src + 3072);
        bf16x4 c0, c1, c2, c3;
        c0[0] = v0[0]; c0[1] = v1[0]; c0[2] = v2[0]; c0[3] = v3[0];
        c1[0] = v0[1]; c1[1] = v1[1]; c1[2] = v2[1]; c1[3] = v3[1];
        c2[0] = v0[2]; c2[1] = v1[2]; c2[2] = v2[2]; c2[3] = v3[2];
        c3[0] = v0[3]; c3[1] = v1[3]; c3[2] = v2[3]; c3[3] = v3[3];
        *(bf16x4*)&smB[h4 + 0][s2q] = c0;
        *(bf16x4*)&smB[h4 + 1][s2q] = c1;
        *(bf16x4*)&smB[h4 + 2][s2q] = c2;
        *(bf16x4*)&smB[h4 + 3][s2q] = c3;
      }
      __syncthreads();
      bf16x8 af[4], bfr[4];
      int sl = l >> 4, lr = l & 15;
#pragma unroll
      for (int i = 0; i < 4; i++) {
        af[i]  = *(const bf16x8*)&smA[wm * 64 + i * 16 + lr][sl * 8];
        bfr[i] = *(const bf16x8*)&smB[wn * 64 + i * 16 + lr][sl * 8];
      }
#pragma unroll
      for (int i = 0; i < 4; i++)
#pragma unroll
        for (int j = 0; j < 4; j++)
          acc[i][j] = __builtin_amdgcn_mfma_f32_16x16x32_bf16(af[i], bfr[j], acc[i][j], 0, 0, 0);
      __syncthreads();
    }
  }
#pragma unroll
  for (int i = 0; i < 4; i++) {
    int m = s1t * 128 + wm * 64 + i * 16 + ((l >> 4) << 2);
#pragma unroll
    for (int j = 0; j < 4; j++) {
      int n = ht * 128 + wn * 64 + j * 16 + (l & 15);
#pragma unroll
      for (int r = 0; r < 4; r++)
        out[(long)(b * SS + m + r) * HH + n] = 0.5f * acc[i][j][r];
    }
  }
}

// ---------------------------------------------------------------------------
extern "C" void kernel_launch(void* const* d_in, const int* in_sizes, int n_in,
                              void* d_out, int out_size, void* d_ws, size_t ws_size,
                              hipStream_t stream)
{
  const size_t SZ_W = (size_t)HH * HH * 2;           //  2 MB
  const size_t SZ_Q = (size_t)5 * BB * SS * HH * 2;  // 84 MB
  const size_t SZ_V = (size_t)5 * BB * SS * SS * 2;  // 21 MB
  const size_t SZ_O = (size_t)5 * BB * SS * HH * 2;  // 84 MB
  const size_t NEED = SZ_W + SZ_Q + SZ_V + SZ_O;     // 191 MB (proven available r4)
  if (ws_size < NEED) {
    canary<<<1, 1, 0, stream>>>((float*)d_out, (float)(ws_size >> 20));
    return;
  }
  char* ws = (char*)d_ws;
  __bf16* Wt  = (__bf16*)ws;
  __bf16* Qb  = (__bf16*)(ws + SZ_W);
  __bf16* Vb  = (__bf16*)(ws + SZ_W + SZ_Q);
  __bf16* Obf = (__bf16*)(ws + SZ_W + SZ_Q + SZ_V);
  const float* o0 = (const float*)d_in[0];
  const float* o1 = (const float*)d_in[1];
  const float* o2 = (const float*)d_in[2];
  const float* o3 = (const float*)d_in[3];
  const float* o4 = (const float*)d_in[4];

  cast_trW<<<256, 256, 0, stream>>>((const float*)d_in[5], Wt);
  cast_all<<<5 * 4096, 256, 0, stream>>>(o0, o1, o2, o3, o4, Obf);
  qgemm256<<<640, 512, 0, stream>>>(Obf, Wt, Qb);
  gram64<<<512, 512, 0, stream>>>(Qb, Obf, Vb);
  pvgemm<<<512, 256, 0, stream>>>(Vb, Obf, (float*)d_out);
}